// Round 1
// baseline (62.808 us; speedup 1.0000x reference)
//
#include <hip/hip_runtime.h>

// AvgPool2d: x (64, 1024, 1024) f32 -> out (64, 512, 512) f32
// out[b][oy][ox] = mean of 2x2 block at (2*oy, 2*ox).
// Flat output-row index row = b*512 + oy maps to input rows 2*row, 2*row+1
// because H = 1024 = 2*512 (batch stride collapses).
//
// One thread computes 2 adjacent outputs: two float4 loads (16B/lane,
// coalesced) + one float2 store (8B/lane, coalesced).

__global__ __launch_bounds__(256) void AvgPool2dLayer_85074712199865_kernel(
    const float* __restrict__ in, float* __restrict__ out, int n_pairs) {
    int t = blockIdx.x * blockDim.x + threadIdx.x;
    if (t >= n_pairs) return;

    int cp  = t & 255;   // column-pair index within the output row (256 pairs = 512 cols)
    int row = t >> 8;    // flat output row in [0, 64*512)

    const size_t in_base = (size_t)(2 * row) * 1024 + (size_t)cp * 4;
    float4 a = *reinterpret_cast<const float4*>(in + in_base);          // input row 2*row
    float4 b = *reinterpret_cast<const float4*>(in + in_base + 1024);   // input row 2*row+1

    float2 o;
    o.x = (a.x + a.y + b.x + b.y) * 0.25f;
    o.y = (a.z + a.w + b.z + b.w) * 0.25f;

    *reinterpret_cast<float2*>(out + (size_t)row * 512 + (size_t)cp * 2) = o;
}

extern "C" void kernel_launch(void* const* d_in, const int* in_sizes, int n_in,
                              void* d_out, int out_size, void* d_ws, size_t ws_size,
                              hipStream_t stream) {
    const float* in = (const float*)d_in[0];
    float* out = (float*)d_out;

    const int n_pairs = 64 * 512 * 256;  // out_size / 2
    const int block = 256;
    const int grid = (n_pairs + block - 1) / block;  // 32768 blocks

    AvgPool2dLayer_85074712199865_kernel<<<grid, block, 0, stream>>>(in, out, n_pairs);
}

// Round 3
// 58.585 us; speedup vs baseline: 1.0721x; 1.0721x over previous
//
#include <hip/hip_runtime.h>

// AvgPool2d: x (64, 1024, 1024) f32 -> out (64, 512, 512) f32
// out[b][oy][ox] = mean of 2x2 block at (2*oy, 2*ox).
// Flat output-row index row = b*512 + oy maps to input rows 2*row, 2*row+1
// (H = 1024 = 2*512, so the batch stride collapses into the row index).
//
// One thread computes 4 adjacent outputs: 4x float4 non-temporal loads
// (2 per input row) + 1x float4 non-temporal store. 80 B of HBM traffic per
// thread; every stream touched exactly once -> nt hints skip cache allocate.
//
// NOTE: __builtin_nontemporal_* requires a clang ext_vector_type, not HIP's
// float4 class (R2 compile failure).

typedef float vf4 __attribute__((ext_vector_type(4)));

__global__ __launch_bounds__(256) void AvgPool2dLayer_85074712199865_kernel(
    const float* __restrict__ in, float* __restrict__ out, int n_quads) {
    int t = blockIdx.x * blockDim.x + threadIdx.x;
    if (t >= n_quads) return;

    int cq  = t & 127;   // quad index within output row (128 quads = 512 cols)
    int row = t >> 7;    // flat output row in [0, 64*512)

    const vf4* r0 = reinterpret_cast<const vf4*>(in + (size_t)(2 * row) * 1024 + (size_t)cq * 8);
    const vf4* r1 = reinterpret_cast<const vf4*>(in + (size_t)(2 * row) * 1024 + 1024 + (size_t)cq * 8);

    vf4 a0 = __builtin_nontemporal_load(r0);
    vf4 a1 = __builtin_nontemporal_load(r0 + 1);
    vf4 b0 = __builtin_nontemporal_load(r1);
    vf4 b1 = __builtin_nontemporal_load(r1 + 1);

    vf4 o;
    o.x = (a0.x + a0.y + b0.x + b0.y) * 0.25f;
    o.y = (a0.z + a0.w + b0.z + b0.w) * 0.25f;
    o.z = (a1.x + a1.y + b1.x + b1.y) * 0.25f;
    o.w = (a1.z + a1.w + b1.z + b1.w) * 0.25f;

    __builtin_nontemporal_store(o, reinterpret_cast<vf4*>(out + (size_t)row * 512 + (size_t)cq * 4));
}

extern "C" void kernel_launch(void* const* d_in, const int* in_sizes, int n_in,
                              void* d_out, int out_size, void* d_ws, size_t ws_size,
                              hipStream_t stream) {
    const float* in = (const float*)d_in[0];
    float* out = (float*)d_out;

    const int n_quads = 64 * 512 * 128;  // out_size / 4 = 4,194,304
    const int block = 256;
    const int grid = (n_quads + block - 1) / block;  // 16384 blocks

    AvgPool2dLayer_85074712199865_kernel<<<grid, block, 0, stream>>>(in, out, n_quads);
}